// Round 8
// baseline (367.552 us; speedup 1.0000x reference)
//
#include <hip/hip_runtime.h>

typedef unsigned short u16;
typedef __attribute__((ext_vector_type(8))) short bf16x8;
typedef __attribute__((ext_vector_type(4))) float f32x4;
typedef __attribute__((ext_vector_type(8))) u16 u16x8;

#define GLOAD_LDS(g, s) __builtin_amdgcn_global_load_lds( \
    (const __attribute__((address_space(1))) void*)(g),   \
    (__attribute__((address_space(3))) void*)(s), 16, 0, 0)

__device__ __forceinline__ u16 f2bf(float f) {
  union { float f; unsigned u; } v; v.f = f;
  unsigned r = v.u + 0x7fffu + ((v.u >> 16) & 1u);
  return (u16)(r >> 16);
}
__device__ __forceinline__ float bf2f(u16 h) {
  union { unsigned u; float f; } v; v.u = ((unsigned)h) << 16;
  return v.f;
}

// inline-asm ds_read_b128 (counted lgkmcnt by hand, rule #18)
__device__ __forceinline__ unsigned lds_a(const u16* p) {
  return (unsigned)(unsigned long long)(__attribute__((address_space(3))) const u16*)p;
}
__device__ __forceinline__ bf16x8 ds128(const u16* p) {
  bf16x8 r;
  asm volatile("ds_read_b128 %0, %1" : "=v"(r) : "v"(lds_a(p)));
  return r;
}

// ================= OLD 128x128 BK=32 core (k_proj only) =================
__device__ __forceinline__ void stage_pair(const u16* gA, int lda, const u16* gB, int ldb,
                                           u16* lA, u16* lB, int wave, int lane) {
  int row = (wave << 4) + (lane >> 2);
  int kb  = (lane & 3) << 3;
  GLOAD_LDS(gA + row * lda + kb,        lA + (wave << 9));
  GLOAD_LDS(gA + (row + 64) * lda + kb, lA + ((wave + 4) << 9));
  GLOAD_LDS(gB + row * ldb + kb,        lB + (wave << 9));
  GLOAD_LDS(gB + (row + 64) * ldb + kb, lB + ((wave + 4) << 9));
}

__device__ __forceinline__ void gemm_seg(f32x4 (&acc)[4][4],
    const u16* Ag, const u16* Bg, int lda, int ldb, int nk,
    u16* As, u16* Bs, int wave, int lane) {
  const int wr = (wave >> 1) << 6, wc = (wave & 1) << 6;
  const int rl = lane & 15, rk = (lane >> 4) << 3;
  stage_pair(Ag, lda, Bg, ldb, As, Bs, wave, lane);
  if (nk > 1)
    stage_pair(Ag + 32, lda, Bg + 32, ldb, As + 4096, Bs + 4096, wave, lane);
  int bufsel = 0;
  for (int kt = 0; kt < nk; ++kt) {
    if (kt + 1 < nk) asm volatile("s_waitcnt vmcnt(4)" ::: "memory");
    else             asm volatile("s_waitcnt vmcnt(0)" ::: "memory");
    __builtin_amdgcn_s_barrier();
    asm volatile("" ::: "memory");
    if (kt + 2 < nk) {
      int nb = bufsel + 2; if (nb >= 3) nb -= 3;
      stage_pair(Ag + (long)(kt + 2) * 32, lda, Bg + (long)(kt + 2) * 32, ldb,
                 As + nb * 4096, Bs + nb * 4096, wave, lane);
    }
    const u16* ab = As + bufsel * 4096;
    const u16* bb = Bs + bufsel * 4096;
    bf16x8 af[4], bfr[4];
#pragma unroll
    for (int i = 0; i < 4; i++)
      af[i]  = *(const bf16x8*)(ab + ((wr + (i << 4) + rl) << 5) + rk);
#pragma unroll
    for (int j = 0; j < 4; j++)
      bfr[j] = *(const bf16x8*)(bb + ((wc + (j << 4) + rl) << 5) + rk);
#pragma unroll
    for (int i = 0; i < 4; i++)
#pragma unroll
      for (int j = 0; j < 4; j++)
        acc[i][j] = __builtin_amdgcn_mfma_f32_16x16x32_bf16(af[i], bfr[j], acc[i][j], 0, 0, 0);
    __builtin_amdgcn_sched_barrier(0);
    bufsel = bufsel + 1; if (bufsel == 3) bufsel = 0;
  }
}

// ====== NEW 128x128 4-wave BK=64 core, 2-buffer, 2 blocks/CU ======
// LDS: As[2][128][64] + Bs[2][128][64] = 64KB -> 2 blocks/CU.
// Swizzle: 16B granule g at g ^ (row&7) on BOTH stage source and ds_read
// (0-conflict, verified r5-7). Pipeline: stage(t+1) issued at top of tile t
// into the other buffer (no read/write overlap); vmcnt(0) + ONE barrier at
// end of tile. Lead time ~= 1 tile; co-resident block covers the remainder.

__device__ __forceinline__ void stage128(const u16* gA, int lda, const u16* gB, int ldb,
                                         u16* Ad, u16* Bd, int tid) {
  int rw = tid >> 3;                          // 0..31 (row within 32-row pass)
  int gs = ((tid & 7) ^ (rw & 7)) << 3;       // swizzled k-offset (elems)
  int wb = (tid >> 6) << 9;                   // wave-uniform LDS base (elems)
#pragma unroll
  for (int p = 0; p < 4; p++) {
    GLOAD_LDS(gA + (long)(p * 32 + rw) * lda + gs, Ad + p * 2048 + wb);
    GLOAD_LDS(gB + (long)(p * 32 + rw) * ldb + gs, Bd + p * 2048 + wb);
  }
}

__device__ __forceinline__ void gemm128(f32x4 (&acc)[4][4],
    const u16* Ag, int lda, const u16* Bg, int ldb, int nk,
    u16* As, u16* Bs, int tid) {
  const int lane = tid & 63, wid = tid >> 6;
  const int wr = (wid >> 1) << 6, wc = (wid & 1) << 6;   // 2x2 wave grid
  const int rl = lane & 15, kg = lane >> 4;
  const int swz0 = (kg ^ (rl & 7)) << 3;
  const int rbA = (wr + rl) * 64, rbB = (wc + rl) * 64;

  stage128(Ag, lda, Bg, ldb, As, Bs, tid);     // tile 0 -> buf 0
  asm volatile("s_waitcnt vmcnt(0)" ::: "memory");
  __builtin_amdgcn_s_barrier();
  for (int t = 0; t < nk; ++t) {
    if (t + 1 < nk)                            // prefetch into other buffer
      stage128(Ag + (t + 1) * 64, lda, Bg + (t + 1) * 64, ldb,
               As + ((t + 1) & 1) * 8192, Bs + ((t + 1) & 1) * 8192, tid);
    const u16* ab = As + (t & 1) * 8192 + rbA;
    const u16* bb = Bs + (t & 1) * 8192 + rbB;
    bf16x8 a0[4], b0[4], a1[4], b1[4];
#pragma unroll
    for (int i = 0; i < 4; i++) a0[i] = ds128(ab + i * 1024 + swz0);
#pragma unroll
    for (int j = 0; j < 4; j++) b0[j] = ds128(bb + j * 1024 + swz0);
#pragma unroll
    for (int i = 0; i < 4; i++) a1[i] = ds128(ab + i * 1024 + (swz0 ^ 32));
#pragma unroll
    for (int j = 0; j < 4; j++) b1[j] = ds128(bb + j * 1024 + (swz0 ^ 32));
    asm volatile("s_waitcnt lgkmcnt(8)" ::: "memory");   // kk0 landed
    __builtin_amdgcn_sched_barrier(0);
    __builtin_amdgcn_s_setprio(1);
#pragma unroll
    for (int i = 0; i < 4; i++)
#pragma unroll
      for (int j = 0; j < 4; j++)
        acc[i][j] = __builtin_amdgcn_mfma_f32_16x16x32_bf16(a0[i], b0[j], acc[i][j], 0, 0, 0);
    __builtin_amdgcn_s_setprio(0);
    asm volatile("s_waitcnt lgkmcnt(0)" ::: "memory");   // kk1 landed
    __builtin_amdgcn_sched_barrier(0);
    __builtin_amdgcn_s_setprio(1);
#pragma unroll
    for (int i = 0; i < 4; i++)
#pragma unroll
      for (int j = 0; j < 4; j++)
        acc[i][j] = __builtin_amdgcn_mfma_f32_16x16x32_bf16(a1[i], b1[j], acc[i][j], 0, 0, 0);
    __builtin_amdgcn_s_setprio(0);
    __builtin_amdgcn_sched_barrier(0);
    if (t + 1 < nk) asm volatile("s_waitcnt vmcnt(0)" ::: "memory");  // stage(t+1) landed
    __builtin_amdgcn_s_barrier();              // reads of buf t done + stage visible
  }
}

// ---------------- conversion kernels ----------------
__global__ __launch_bounds__(256) void k_cvt2(const float* __restrict__ inX,
                                              const float* __restrict__ inY,
                                              u16* __restrict__ oX, u16* __restrict__ oY,
                                              int n8) {
  int i = blockIdx.x * 256 + threadIdx.x;
  const float* in = (i < n8) ? inX : inY;
  u16* out = (i < n8) ? oX : oY;
  int k = (i < n8) ? i : i - n8;
  const float4* pf = (const float4*)in + (long)k * 2;
  float4 a = pf[0], b = pf[1];
  u16x8 o;
  o[0] = f2bf(a.x); o[1] = f2bf(a.y); o[2] = f2bf(a.z); o[3] = f2bf(a.w);
  o[4] = f2bf(b.x); o[5] = f2bf(b.y); o[6] = f2bf(b.z); o[7] = f2bf(b.w);
  *((u16x8*)out + k) = o;
}

struct P6 { const float* p[6]; };
struct O6 { u16* p[6]; };

__global__ __launch_bounds__(256) void k_cvt_w(P6 w, u16* __restrict__ out) {
  int z = blockIdx.y;
  int i = blockIdx.x * 256 + threadIdx.x;
  const float4* pf = (const float4*)w.p[z] + (long)i * 2;
  float4 a = pf[0], b = pf[1];
  u16x8 o;
  o[0] = f2bf(a.x); o[1] = f2bf(a.y); o[2] = f2bf(a.z); o[3] = f2bf(a.w);
  o[4] = f2bf(b.x); o[5] = f2bf(b.y); o[6] = f2bf(b.z); o[7] = f2bf(b.w);
  *((u16x8*)(out + (long)z * 262144) + i) = o;
}

// ---------------- projections (old core, 1D bm-chunked grid) ----------------
__global__ __launch_bounds__(256) void k_proj(const u16* __restrict__ Xb, const u16* __restrict__ Yb,
                                              const u16* __restrict__ Wb, P6 bias, O6 dst) {
  __shared__ u16 As[12288], Bs[12288];
  int x = blockIdx.x;
  int swz = (x & 7) * 384 + (x >> 3);
  int bm = swz / 24;
  int r  = swz - bm * 24;
  int z = r >> 2, bn = r & 3;
  int tid = threadIdx.x, wave = tid >> 6, lane = tid & 63;
  const u16* Ag = (z < 3 ? Xb : Yb) + (long)bm * 128 * 512;
  const u16* Bg = Wb + (long)z * 262144 + (long)bn * 128 * 512;
  f32x4 acc[4][4] = {};
  gemm_seg(acc, Ag, Bg, 512, 512, 16, As, Bs, wave, lane);
  const float* bi = bias.p[z];
  u16* D = dst.p[z];
  int wr = (wave >> 1) << 6, wc = (wave & 1) << 6;
  int row0 = bm * 128 + wr + ((lane >> 4) << 2);
  int col0 = bn * 128 + wc + (lane & 15);
  float bj[4];
#pragma unroll
  for (int j = 0; j < 4; j++) bj[j] = bi[col0 + (j << 4)];
#pragma unroll
  for (int i = 0; i < 4; i++)
#pragma unroll
    for (int j = 0; j < 4; j++)
#pragma unroll
      for (int rr = 0; rr < 4; rr++)
        D[(long)(row0 + (i << 4) + rr) * 512 + col0 + (j << 4)] = f2bf(acc[i][j][rr] + bj[j]);
}

// ---------------- scores (gemm128): XCD chunk = one batch b ----------------
__global__ __launch_bounds__(256) void k_s(const u16* __restrict__ Q, const u16* __restrict__ K,
                                           u16* __restrict__ S) {
  __shared__ u16 As[16384], Bs[16384];
  int x = blockIdx.x;
  int swz = (x & 7) * 256 + (x >> 3);        // 2048 blocks, chunk=256 = one b
  int bn = swz & 15, bm = (swz >> 4) & 15, b = swz >> 8;
  int tid = threadIdx.x;
  const u16* Ag = Q + (long)b * 1048576 + (long)bm * 128 * 512;
  const u16* Bg = K + (long)b * 1048576 + (long)bn * 128 * 512;
  f32x4 acc[4][4] = {};
  gemm128(acc, Ag, 512, Bg, 512, 8, As, Bs, tid);
  u16* D = S + (long)b * 4194304;
  const float scale = 0.04419417382415922f;  // 1/sqrt(512)
  int lane = tid & 63, wid = tid >> 6;
  int wr = (wid >> 1) << 6, wc = (wid & 1) << 6;
  int row0 = bm * 128 + wr + ((lane >> 4) << 2);
  int col0 = bn * 128 + wc + (lane & 15);
#pragma unroll
  for (int i = 0; i < 4; i++)
#pragma unroll
    for (int j = 0; j < 4; j++)
#pragma unroll
      for (int rr = 0; rr < 4; rr++)
        D[(long)(row0 + (i << 4) + rr) * 2048 + col0 + (j << 4)] = f2bf(acc[i][j][rr] * scale);
}

// ---------------- softmax over batch axis ----------------
__global__ __launch_bounds__(256) void k_softmax(u16* __restrict__ S) {
  int idx = blockIdx.x * 256 + threadIdx.x;
  u16x8 v[8];
#pragma unroll
  for (int b = 0; b < 8; b++) v[b] = *((const u16x8*)(S + (long)b * 4194304) + idx);
#pragma unroll
  for (int j = 0; j < 8; j++) {
    float e[8], m = -1e30f;
#pragma unroll
    for (int b = 0; b < 8; b++) { e[b] = bf2f(v[b][j]); m = fmaxf(m, e[b]); }
    float s = 0.f;
#pragma unroll
    for (int b = 0; b < 8; b++) { e[b] = __expf(e[b] - m); s += e[b]; }
    float inv = 1.0f / s;
#pragma unroll
    for (int b = 0; b < 8; b++) v[b][j] = f2bf(e[b] * inv);
  }
#pragma unroll
  for (int b = 0; b < 8; b++) *((u16x8*)(S + (long)b * 4194304) + idx) = v[b];
}

// ---------------- V transpose ----------------
__global__ __launch_bounds__(256) void k_tr(const u16* __restrict__ V1, const u16* __restrict__ V2,
                                            u16* __restrict__ T1, u16* __restrict__ T2) {
  __shared__ u16 tile[64][65];
  int z = blockIdx.z;
  const u16* src = (z < 8 ? V1 : V2) + (long)(z & 7) * 1048576;
  u16*       dst = (z < 8 ? T1 : T2) + (long)(z & 7) * 1048576;
  int n0 = blockIdx.x * 64, d0 = blockIdx.y * 64;
  int t = threadIdx.x;
  int r = t >> 2, cs = (t & 3) * 16;
  const u16x8* sp = (const u16x8*)(src + (long)(n0 + r) * 512 + d0 + cs);
  u16x8 a = sp[0], b = sp[1];
#pragma unroll
  for (int jj = 0; jj < 8; jj++) { tile[r][cs + jj] = a[jj]; tile[r][cs + 8 + jj] = b[jj]; }
  __syncthreads();
  u16x8 o0, o1;
#pragma unroll
  for (int jj = 0; jj < 8; jj++) { o0[jj] = tile[cs + jj][r]; o1[jj] = tile[cs + 8 + jj][r]; }
  u16x8* op = (u16x8*)(dst + (long)(d0 + r) * 2048 + n0 + cs);
  op[0] = o0; op[1] = o1;
}

// ---------------- PV (gemm128): XCD chunk = one batch b ----------------
// mode 0: out = acc + X + Y ; mode 1: out += acc
__global__ __launch_bounds__(256) void k_pv(const u16* __restrict__ A, const u16* __restrict__ Vt,
                                            const float* __restrict__ X, const float* __restrict__ Y,
                                            float* __restrict__ out, int mode) {
  __shared__ u16 As[16384], Bs[16384];
  int x = blockIdx.x;
  int swz = (x & 7) * 64 + (x >> 3);         // 512 blocks, chunk=64 = one b
  int bn = swz & 3, bm = (swz >> 2) & 15, b = swz >> 6;
  int tid = threadIdx.x;
  const u16* Ag = A + (long)b * 4194304 + (long)bm * 128 * 2048;
  const u16* Bg = Vt + (long)b * 1048576 + (long)bn * 128 * 2048;
  f32x4 acc[4][4] = {};
  gemm128(acc, Ag, 2048, Bg, 2048, 32, As, Bs, tid);
  int lane = tid & 63, wid = tid >> 6;
  int wr = (wid >> 1) << 6, wc = (wid & 1) << 6;
  int row0 = bm * 128 + wr + ((lane >> 4) << 2);
  int col0 = bn * 128 + wc + (lane & 15);
  long base = (long)b * 1048576;
#pragma unroll
  for (int i = 0; i < 4; i++)
#pragma unroll
    for (int j = 0; j < 4; j++)
#pragma unroll
      for (int rr = 0; rr < 4; rr++) {
        long idx = base + (long)(row0 + (i << 4) + rr) * 512 + col0 + (j << 4);
        float v = acc[i][j][rr];
        out[idx] = mode ? (out[idx] + v) : (v + X[idx] + Y[idx]);
      }
}

extern "C" void kernel_launch(void* const* d_in, const int* in_sizes, int n_in,
                              void* d_out, int out_size, void* d_ws, size_t ws_size,
                              hipStream_t stream) {
  const float* X = (const float*)d_in[0];
  const float* Y = (const float*)d_in[1];
  P6 wp, bp;
  for (int i = 0; i < 6; i++) { wp.p[i] = (const float*)d_in[2 + 2 * i]; bp.p[i] = (const float*)d_in[3 + 2 * i]; }

  const long NX = 8L * 2048 * 512;
  const long NS = 8L * 2048 * 2048;
  u16* p = (u16*)d_ws;
  u16* Xb = p;  p += NX;                  // bf16 X (reused as Vt1)
  u16* Yb = p;  p += NX;                  // bf16 Y (reused as Vt2)
  u16* Wb = p;  p += 6L * 512 * 512;
  u16* Q1 = p;  p += NX;
  u16* K2 = p;  p += NX;
  u16* Q2 = p;  p += NX;
  u16* K1 = p;  p += NX;
  u16* Sb = p;  p += NS;
  u16* V1 = Sb;
  u16* V2 = Sb + NX;
  u16* Vt1 = Xb;
  u16* Vt2 = Yb;
  (void)ws_size; (void)in_sizes; (void)n_in; (void)out_size;

  dim3 T(256);
  k_cvt2<<<dim3(8192), T, 0, stream>>>(X, Y, Xb, Yb, (int)(NX / 8));
  k_cvt_w<<<dim3(128, 6), T, 0, stream>>>(wp, Wb);
  O6 dst; dst.p[0] = Q1; dst.p[1] = K1; dst.p[2] = V1; dst.p[3] = Q2; dst.p[4] = K2; dst.p[5] = V2;
  k_proj<<<dim3(3072), T, 0, stream>>>(Xb, Yb, Wb, bp, dst);
  k_tr<<<dim3(32, 8, 16), T, 0, stream>>>(V1, V2, Vt1, Vt2);
  // attention 2 first: S2 = Q2.K1^T, softmax over b, out = A2.V1 + X + Y
  k_s<<<dim3(2048), T, 0, stream>>>(Q2, K1, Sb);
  k_softmax<<<dim3(2048), T, 0, stream>>>(Sb);
  k_pv<<<dim3(512), T, 0, stream>>>(Sb, Vt1, X, Y, (float*)d_out, 0);
  // attention 1: S1 = Q1.K2^T, softmax, out += A1.V2
  k_s<<<dim3(2048), T, 0, stream>>>(Q1, K2, Sb);
  k_softmax<<<dim3(2048), T, 0, stream>>>(Sb);
  k_pv<<<dim3(512), T, 0, stream>>>(Sb, Vt2, X, Y, (float*)d_out, 1);
}